// Round 1
// baseline (1537.743 us; speedup 1.0000x reference)
//
#include <hip/hip_runtime.h>
#include <math.h>

// ---------------------------------------------------------------------------
// Problem: ConvAttention (B=32, T1=1600, T2=400, n_mel=80, n_text=512, n_att=80)
//   k = relu(conv1d(keys, kw1[1024,512,3], pad1)); k = conv1d(k, kw2[80,1024,1])
//   q = relu(conv1d(queries, qw1[160,80,3], pad1)); q = relu(conv1d(q, qw2[80,160,1]))
//   q = conv1d(q, qw3[80,80,1])
//   attn = -5e-4*(|q|^2 + |k|^2 - 2 q.k); logprob = log_softmax_s(attn) + log(prior+1e-8)
//   attn_out = softmax_s(where(mask, -inf, logprob))
// Outputs: [attn (32*1*1600*400), logprob (same)] concatenated f32.
// ---------------------------------------------------------------------------

// ---------------- Tiled conv1d (GEMM-style), f32 ----------------
// out[b,co,t] = act( bias[co] + sum_ci sum_tap w[co,ci,tap] * in[b,ci,t+tap-PAD] )
// Block computes a 64(co) x 64(t) tile for one b. K-loop over ci in chunks of 16.
template <int KTAP, bool RELU>
__global__ __launch_bounds__(256) void conv1d_tiled(
    const float* __restrict__ in, const float* __restrict__ wgt,
    const float* __restrict__ bias, float* __restrict__ out,
    int Cin, int Cout, int T)
{
    constexpr int PAD = (KTAP - 1) / 2;
    constexpr int XW  = 64 + 2 * PAD;   // staged input width
    constexpr int KC  = 16;             // ci chunk

    __shared__ float Wl[KC * KTAP][64]; // [kc*KTAP+tap][co_local]
    __shared__ float Xl[KC][XW];        // [kc][t_local]

    const int tid = threadIdx.x;
    const int tx  = tid & 15;   // -> 4 co each
    const int ty  = tid >> 4;   // -> 4 t each
    const int t0  = blockIdx.x * 64;
    const int co0 = blockIdx.y * 64;
    const int b   = blockIdx.z;

    const float* inb = in + (size_t)b * Cin * T;

    float acc[4][4];
#pragma unroll
    for (int i = 0; i < 4; i++)
#pragma unroll
        for (int j = 0; j < 4; j++) acc[i][j] = 0.f;

    for (int ci0 = 0; ci0 < Cin; ci0 += KC) {
        __syncthreads();
        // stage W chunk: w[co][ci0+kc][tap] ; r = kc*KTAP+tap is contiguous in memory
        for (int idx = tid; idx < 64 * KC * KTAP; idx += 256) {
            int col = idx / (KC * KTAP);
            int r   = idx - col * (KC * KTAP);
            int co  = co0 + col;
            float v = 0.f;
            if (co < Cout)
                v = wgt[(size_t)co * Cin * KTAP + (size_t)ci0 * KTAP + r];
            Wl[r][col] = v;
        }
        // stage X chunk: in[b][ci0+kc][t0-PAD .. t0+63+PAD]
        for (int idx = tid; idx < KC * XW; idx += 256) {
            int kc = idx / XW;
            int tt = idx - kc * XW;
            int t  = t0 - PAD + tt;
            float v = 0.f;
            if (t >= 0 && t < T) v = inb[(size_t)(ci0 + kc) * T + t];
            Xl[kc][tt] = v;
        }
        __syncthreads();

#pragma unroll
        for (int kc = 0; kc < KC; kc++) {
            float xs[4 + KTAP - 1];
#pragma unroll
            for (int u = 0; u < 4 + KTAP - 1; u++) xs[u] = Xl[kc][ty * 4 + u];
#pragma unroll
            for (int tap = 0; tap < KTAP; tap++) {
                float4 wv = *(const float4*)&Wl[kc * KTAP + tap][tx * 4];
                const float* wf = (const float*)&wv;
#pragma unroll
                for (int i = 0; i < 4; i++) {
#pragma unroll
                    for (int j = 0; j < 4; j++)
                        acc[i][j] = fmaf(wf[i], xs[j + tap], acc[i][j]);
                }
            }
        }
    }

#pragma unroll
    for (int i = 0; i < 4; i++) {
        int co = co0 + tx * 4 + i;
        if (co >= Cout) continue;
        float bv = bias[co];
#pragma unroll
        for (int j = 0; j < 4; j++) {
            int t = t0 + ty * 4 + j;
            if (t >= T) continue;
            float v = acc[i][j] + bv;
            if (RELU) v = fmaxf(v, 0.f);
            out[((size_t)b * Cout + co) * T + t] = v;
        }
    }
}

// ---------------- per-position squared channel sum ----------------
__global__ __launch_bounds__(256) void sqsum_kernel(
    const float* __restrict__ x, float* __restrict__ out, int C, int T, int total)
{
    int idx = blockIdx.x * 256 + threadIdx.x;
    if (idx >= total) return;
    int b = idx / T;
    int t = idx - b * T;
    const float* xb = x + (size_t)b * C * T + t;
    float s = 0.f;
    for (int c = 0; c < C; c++) {
        float v = xb[(size_t)c * T];
        s = fmaf(v, v, s);
    }
    out[idx] = s;
}

// ---------------- fused QK + softmax/logprob ----------------
// Block: 256 thr = 4 waves; each wave owns 2 query rows (block: 8 rows of one b).
// Each lane holds 7 key positions (s = lane + 64*j). K2 staged in LDS by c-chunks.
#define NS 7
__global__ __launch_bounds__(256) void attn_kernel(
    const float* __restrict__ K2, const float* __restrict__ Q3,
    const float* __restrict__ k2s, const float* __restrict__ q2s,
    const float* __restrict__ prior, const int* __restrict__ mask,
    float* __restrict__ out_attn, float* __restrict__ out_lp)
{
    const int T1 = 1600, T2 = 400, C = 80;
    __shared__ float Kl[16][448]; // 400 used; tail cols read-but-ignored
    __shared__ float Ql[8][16];

    const int tid  = threadIdx.x;
    const int lane = tid & 63;
    const int wave = tid >> 6;
    const int b    = blockIdx.y;
    const int t0   = blockIdx.x * 8;

    float sc[2][NS];
#pragma unroll
    for (int r = 0; r < 2; r++)
#pragma unroll
        for (int j = 0; j < NS; j++) sc[r][j] = 0.f;

    for (int c0 = 0; c0 < C; c0 += 16) {
        __syncthreads();
        for (int idx = tid; idx < 16 * T2; idx += 256) {
            int c = idx / T2, s = idx - c * T2;
            Kl[c][s] = K2[((size_t)b * C + c0 + c) * T2 + s];
        }
        if (tid < 128) {
            int rr = tid >> 4, c = tid & 15;
            Ql[rr][c] = Q3[((size_t)b * C + c0 + c) * T1 + (t0 + rr)];
        }
        __syncthreads();
#pragma unroll
        for (int c = 0; c < 16; c++) {
            float kv[NS];
#pragma unroll
            for (int j = 0; j < NS; j++) kv[j] = Kl[c][lane + 64 * j];
            float q0 = Ql[wave * 2 + 0][c];
            float q1 = Ql[wave * 2 + 1][c];
#pragma unroll
            for (int j = 0; j < NS; j++) {
                sc[0][j] = fmaf(q0, kv[j], sc[0][j]);
                sc[1][j] = fmaf(q1, kv[j], sc[1][j]);
            }
        }
    }

    // key-side terms (shared by both rows of this wave)
    float k2v[NS];
    int   mk[NS];
#pragma unroll
    for (int j = 0; j < NS; j++) {
        int s = lane + 64 * j;
        k2v[j] = (s < T2) ? k2s[b * T2 + s] : 0.f;
        mk[j]  = (s < T2) ? mask[b * T2 + s] : 1;
    }

    for (int r = 0; r < 2; r++) {
        int t = t0 + wave * 2 + r;
        float q2v = q2s[b * T1 + t];

        float scr[NS];
        float m = -INFINITY;
#pragma unroll
        for (int j = 0; j < NS; j++) {
            int s = lane + 64 * j;
            if (s < T2) {
                scr[j] = fmaf(1e-3f, sc[r][j], -5e-4f * (q2v + k2v[j]));
                m = fmaxf(m, scr[j]);
            } else {
                scr[j] = -INFINITY;
            }
        }
#pragma unroll
        for (int o = 32; o >= 1; o >>= 1) m = fmaxf(m, __shfl_xor(m, o));
        float sum = 0.f;
#pragma unroll
        for (int j = 0; j < NS; j++) {
            int s = lane + 64 * j;
            if (s < T2) sum += expf(scr[j] - m);
        }
#pragma unroll
        for (int o = 32; o >= 1; o >>= 1) sum += __shfl_xor(sum, o);
        float lse = m + logf(sum);

        const float* pr = prior + ((size_t)b * T1 + t) * T2;
        float* lpout = out_lp + ((size_t)b * T1 + t) * T2;
        float* atout = out_attn + ((size_t)b * T1 + t) * T2;

        float val[NS];
        float m2 = -INFINITY;
#pragma unroll
        for (int j = 0; j < NS; j++) {
            int s = lane + 64 * j;
            if (s < T2) {
                float lp = scr[j] - lse + logf(pr[s] + 1e-8f);
                lpout[s] = lp;
                val[j] = mk[j] ? -INFINITY : lp;
                m2 = fmaxf(m2, val[j]);
            } else {
                val[j] = -INFINITY;
            }
        }
#pragma unroll
        for (int o = 32; o >= 1; o >>= 1) m2 = fmaxf(m2, __shfl_xor(m2, o));
        float sum2 = 0.f;
#pragma unroll
        for (int j = 0; j < NS; j++) sum2 += expf(val[j] - m2); // -inf -> 0
#pragma unroll
        for (int o = 32; o >= 1; o >>= 1) sum2 += __shfl_xor(sum2, o);
        float inv = 1.f / sum2;
#pragma unroll
        for (int j = 0; j < NS; j++) {
            int s = lane + 64 * j;
            if (s < T2) atout[s] = expf(val[j] - m2) * inv;
        }
    }
}

// ---------------------------------------------------------------------------
extern "C" void kernel_launch(void* const* d_in, const int* in_sizes, int n_in,
                              void* d_out, int out_size, void* d_ws, size_t ws_size,
                              hipStream_t stream)
{
    (void)in_sizes; (void)n_in; (void)out_size; (void)ws_size;

    const float* queries = (const float*)d_in[0];  // (32,80,1600)
    const float* keys    = (const float*)d_in[1];  // (32,512,400)
    const float* prior   = (const float*)d_in[2];  // (32,1600,400)
    const int*   mask    = (const int*)d_in[3];    // (32,400,1) bool->int
    const float* kw1     = (const float*)d_in[4];  // (1024,512,3)
    const float* kb1     = (const float*)d_in[5];
    const float* kw2     = (const float*)d_in[6];  // (80,1024,1)
    const float* kb2     = (const float*)d_in[7];
    const float* qw1     = (const float*)d_in[8];  // (160,80,3)
    const float* qb1     = (const float*)d_in[9];
    const float* qw2     = (const float*)d_in[10]; // (80,160,1)
    const float* qb2     = (const float*)d_in[11];
    const float* qw3     = (const float*)d_in[12]; // (80,80,1)
    const float* qb3     = (const float*)d_in[13];

    float* ws  = (float*)d_ws;
    float* K1  = ws;              // 32*1024*400 = 13,107,200 f  (also reused as Q1)
    float* K2  = ws + 13107200;   // 32*80*400   =  1,024,000 f
    float* Q2  = ws + 14131200;   // 32*80*1600  =  4,096,000 f
    float* Q3  = ws + 18227200;   // 4,096,000 f
    float* k2s = ws + 22323200;   // 12,800 f
    float* q2s = ws + 22336000;   // 51,200 f
    float* Q1  = K1;              // 32*160*1600 = 8,192,000 f <= K1 region

    float* out_attn = (float*)d_out;
    float* out_lp   = out_attn + (size_t)32 * 1600 * 400;

    dim3 blk(256);

    // key path
    conv1d_tiled<3, true ><<<dim3(7, 16, 32), blk, 0, stream>>>(keys, kw1, kb1, K1, 512, 1024, 400);
    conv1d_tiled<1, false><<<dim3(7,  2, 32), blk, 0, stream>>>(K1,   kw2, kb2, K2, 1024,  80, 400);
    // query path
    conv1d_tiled<3, true ><<<dim3(25, 3, 32), blk, 0, stream>>>(queries, qw1, qb1, Q1,  80, 160, 1600);
    conv1d_tiled<1, true ><<<dim3(25, 2, 32), blk, 0, stream>>>(Q1,      qw2, qb2, Q2, 160,  80, 1600);
    conv1d_tiled<1, false><<<dim3(25, 2, 32), blk, 0, stream>>>(Q2,      qw3, qb3, Q3,  80,  80, 1600);
    // squared norms
    sqsum_kernel<<<(32 * 400  + 255) / 256, blk, 0, stream>>>(K2, k2s, 80, 400,  32 * 400);
    sqsum_kernel<<<(32 * 1600 + 255) / 256, blk, 0, stream>>>(Q3, q2s, 80, 1600, 32 * 1600);
    // fused attention + softmaxes
    attn_kernel<<<dim3(200, 32), blk, 0, stream>>>(K2, Q3, k2s, q2s, prior, mask, out_attn, out_lp);
}

// Round 2
// 759.923 us; speedup vs baseline: 2.0236x; 2.0236x over previous
//
#include <hip/hip_runtime.h>
#include <math.h>

// ---------------------------------------------------------------------------
// ConvAttention (B=32, T1=1600, T2=400, n_mel=80, n_text=512, n_att=80)
// Round 2: key conv1 (512->1024, k=3) moved to bf16 MFMA GEMM.
//   GEMM: M=1024 (co), N=32*404 (b,t padded), K=512*3 taps.
//   Xt[b*404 + t + 1][ci] bf16 (rows 0,401..403 zero) -> tap d reads row n+d.
// ---------------------------------------------------------------------------

typedef __attribute__((ext_vector_type(8))) short bf16x8;
typedef __attribute__((ext_vector_type(4))) float f32x4;

static __device__ __forceinline__ unsigned short f2bf(float f) {
    union { float f; unsigned u; } v; v.f = f;
    unsigned r = v.u + 0x7FFF + ((v.u >> 16) & 1);
    return (unsigned short)(r >> 16);
}

// ---------------- converters ----------------
__global__ __launch_bounds__(256) void convert_w(
    const float* __restrict__ w, unsigned short* __restrict__ Wbf)
{
    int idx = blockIdx.x * 256 + threadIdx.x;
    if (idx >= 1024 * 512 * 3) return;
    int d   = idx / (1024 * 512);
    int rem = idx - d * 1024 * 512;
    int co  = rem >> 9, ci = rem & 511;
    Wbf[idx] = f2bf(w[((size_t)co * 512 + ci) * 3 + d]);
}

// keys [32][512][400] f32 -> Xt [32*404+4][512] bf16, row b*404+tr holds t=tr-1
__global__ __launch_bounds__(256) void convert_x(
    const float* __restrict__ keys, unsigned short* __restrict__ Xt)
{
    __shared__ float s[32][33];
    int b = blockIdx.z, ci0 = blockIdx.y * 32, tr0 = blockIdx.x * 32;
    int tx = threadIdx.x & 31, ty = threadIdx.x >> 5; // 32 x 8
#pragma unroll
    for (int i = 0; i < 4; i++) {
        int ci = ci0 + ty + 8 * i;
        int t_in = tr0 + tx - 1;
        float v = (t_in >= 0 && t_in < 400) ? keys[((size_t)b * 512 + ci) * 400 + t_in] : 0.f;
        s[ty + 8 * i][tx] = v;
    }
    __syncthreads();
#pragma unroll
    for (int i = 0; i < 4; i++) {
        int tr = tr0 + ty + 8 * i;
        if (tr < 404)
            Xt[((size_t)b * 404 + tr) * 512 + ci0 + tx] = f2bf(s[tx][ty + 8 * i]);
    }
}

__global__ __launch_bounds__(256) void zero_tail(unsigned short* __restrict__ Xt)
{
    int i = blockIdx.x * 256 + threadIdx.x;
    if (i < 4 * 512) Xt[(size_t)12928 * 512 + i] = 0;
}

// ---------------- conv1 as bf16 MFMA GEMM ----------------
__global__ __launch_bounds__(256) void conv1_mfma(
    const unsigned short* __restrict__ Wbf,  // [3][1024][512]
    const unsigned short* __restrict__ Xt,   // [12932][512]
    const float* __restrict__ bias,          // [1024]
    float* __restrict__ out)                 // [32][1024][400]
{
    constexpr int LDW = 40; // lds row stride (32 + 8 pad) -> conflict-free b128
    __shared__ unsigned short Al[128 * LDW];
    __shared__ unsigned short Bl[128 * LDW];

    const int tid  = threadIdx.x;
    const int lane = tid & 63;
    const int wid  = tid >> 6;
    const int wm   = wid >> 1;
    const int wn   = wid & 1;
    const int co0  = blockIdx.y * 128;
    const int n0   = blockIdx.x * 128;

    const int r0 = tid >> 2;            // staging row, chunk 0 (0..63)
    const int r1 = r0 + 64;             // chunk 1 (64..127)
    const int q0 = (tid & 3) * 8;       // ci sub-offset

    f32x4 acc[4][4] = {};

    bf16x8 ra0, ra1, rb0, rb1;
    // prefetch kk = 0 (d=0, ci0=0)
    ra0 = *(const bf16x8*)&Wbf[(size_t)(co0 + r0) * 512 + q0];
    ra1 = *(const bf16x8*)&Wbf[(size_t)(co0 + r1) * 512 + q0];
    rb0 = *(const bf16x8*)&Xt[(size_t)(n0 + r0) * 512 + q0];
    rb1 = *(const bf16x8*)&Xt[(size_t)(n0 + r1) * 512 + q0];

    const int fr = lane & 15;           // fragment M/N index
    const int ko = (lane >> 4) * 8;     // fragment k offset

    for (int kk = 0; kk < 48; kk++) {
        __syncthreads();
        *(bf16x8*)&Al[r0 * LDW + q0] = ra0;
        *(bf16x8*)&Al[r1 * LDW + q0] = ra1;
        *(bf16x8*)&Bl[r0 * LDW + q0] = rb0;
        *(bf16x8*)&Bl[r1 * LDW + q0] = rb1;
        __syncthreads();

        if (kk < 47) {
            int nk = kk + 1;
            int d = nk >> 4, ci0 = (nk & 15) * 32;
            ra0 = *(const bf16x8*)&Wbf[((size_t)d * 1024 + co0 + r0) * 512 + ci0 + q0];
            ra1 = *(const bf16x8*)&Wbf[((size_t)d * 1024 + co0 + r1) * 512 + ci0 + q0];
            rb0 = *(const bf16x8*)&Xt[(size_t)(n0 + d + r0) * 512 + ci0 + q0];
            rb1 = *(const bf16x8*)&Xt[(size_t)(n0 + d + r1) * 512 + ci0 + q0];
        }

        bf16x8 af[4], bfr[4];
#pragma unroll
        for (int mi = 0; mi < 4; mi++)
            af[mi] = *(const bf16x8*)&Al[(wm * 64 + mi * 16 + fr) * LDW + ko];
#pragma unroll
        for (int ni = 0; ni < 4; ni++)
            bfr[ni] = *(const bf16x8*)&Bl[(wn * 64 + ni * 16 + fr) * LDW + ko];
#pragma unroll
        for (int mi = 0; mi < 4; mi++)
#pragma unroll
            for (int ni = 0; ni < 4; ni++)
                acc[mi][ni] = __builtin_amdgcn_mfma_f32_16x16x32_bf16(
                    af[mi], bfr[ni], acc[mi][ni], 0, 0, 0);
    }

    // epilogue: C[co][n] ; col=lane&15 -> n, row=(lane>>4)*4+r -> co
#pragma unroll
    for (int mi = 0; mi < 4; mi++) {
#pragma unroll
        for (int r = 0; r < 4; r++) {
            int co = co0 + wm * 64 + mi * 16 + (lane >> 4) * 4 + r;
            float bv = bias[co];
#pragma unroll
            for (int ni = 0; ni < 4; ni++) {
                int n = n0 + wn * 64 + ni * 16 + fr;
                int b = n / 404;
                int t = n - b * 404;
                if (t < 400)
                    out[((size_t)b * 1024 + co) * 400 + t] =
                        fmaxf(acc[mi][ni][r] + bv, 0.f);
            }
        }
    }
}

// ---------------- Tiled conv1d (GEMM-style), f32 ----------------
template <int KTAP, bool RELU>
__global__ __launch_bounds__(256) void conv1d_tiled(
    const float* __restrict__ in, const float* __restrict__ wgt,
    const float* __restrict__ bias, float* __restrict__ out,
    int Cin, int Cout, int T)
{
    constexpr int PAD = (KTAP - 1) / 2;
    constexpr int XW  = 64 + 2 * PAD;
    constexpr int KC  = 16;

    __shared__ float Wl[KC * KTAP][64];
    __shared__ float Xl[KC][XW];

    const int tid = threadIdx.x;
    const int tx  = tid & 15;
    const int ty  = tid >> 4;
    const int t0  = blockIdx.x * 64;
    const int co0 = blockIdx.y * 64;
    const int b   = blockIdx.z;

    const float* inb = in + (size_t)b * Cin * T;

    float acc[4][4];
#pragma unroll
    for (int i = 0; i < 4; i++)
#pragma unroll
        for (int j = 0; j < 4; j++) acc[i][j] = 0.f;

    for (int ci0 = 0; ci0 < Cin; ci0 += KC) {
        __syncthreads();
        for (int idx = tid; idx < 64 * KC * KTAP; idx += 256) {
            int col = idx / (KC * KTAP);
            int r   = idx - col * (KC * KTAP);
            int co  = co0 + col;
            float v = 0.f;
            if (co < Cout)
                v = wgt[(size_t)co * Cin * KTAP + (size_t)ci0 * KTAP + r];
            Wl[r][col] = v;
        }
        for (int idx = tid; idx < KC * XW; idx += 256) {
            int kc = idx / XW;
            int tt = idx - kc * XW;
            int t  = t0 - PAD + tt;
            float v = 0.f;
            if (t >= 0 && t < T) v = inb[(size_t)(ci0 + kc) * T + t];
            Xl[kc][tt] = v;
        }
        __syncthreads();

#pragma unroll
        for (int kc = 0; kc < KC; kc++) {
            float xs[4 + KTAP - 1];
#pragma unroll
            for (int u = 0; u < 4 + KTAP - 1; u++) xs[u] = Xl[kc][ty * 4 + u];
#pragma unroll
            for (int tap = 0; tap < KTAP; tap++) {
                float4 wv = *(const float4*)&Wl[kc * KTAP + tap][tx * 4];
                const float* wf = (const float*)&wv;
#pragma unroll
                for (int i = 0; i < 4; i++) {
#pragma unroll
                    for (int j = 0; j < 4; j++)
                        acc[i][j] = fmaf(wf[i], xs[j + tap], acc[i][j]);
                }
            }
        }
    }

#pragma unroll
    for (int i = 0; i < 4; i++) {
        int co = co0 + tx * 4 + i;
        if (co >= Cout) continue;
        float bv = bias[co];
#pragma unroll
        for (int j = 0; j < 4; j++) {
            int t = t0 + ty * 4 + j;
            if (t >= T) continue;
            float v = acc[i][j] + bv;
            if (RELU) v = fmaxf(v, 0.f);
            out[((size_t)b * Cout + co) * T + t] = v;
        }
    }
}

// ---------------- per-position squared channel sum ----------------
__global__ __launch_bounds__(256) void sqsum_kernel(
    const float* __restrict__ x, float* __restrict__ out, int C, int T, int total)
{
    int idx = blockIdx.x * 256 + threadIdx.x;
    if (idx >= total) return;
    int b = idx / T;
    int t = idx - b * T;
    const float* xb = x + (size_t)b * C * T + t;
    float s = 0.f;
    for (int c = 0; c < C; c++) {
        float v = xb[(size_t)c * T];
        s = fmaf(v, v, s);
    }
    out[idx] = s;
}

// ---------------- fused QK + softmax/logprob ----------------
#define NS 7
__global__ __launch_bounds__(256) void attn_kernel(
    const float* __restrict__ K2, const float* __restrict__ Q3,
    const float* __restrict__ k2s, const float* __restrict__ q2s,
    const float* __restrict__ prior, const int* __restrict__ mask,
    float* __restrict__ out_attn, float* __restrict__ out_lp)
{
    const int T1 = 1600, T2 = 400, C = 80;
    __shared__ float Kl[16][448];
    __shared__ float Ql[8][16];

    const int tid  = threadIdx.x;
    const int lane = tid & 63;
    const int wave = tid >> 6;
    const int b    = blockIdx.y;
    const int t0   = blockIdx.x * 8;

    float sc[2][NS];
#pragma unroll
    for (int r = 0; r < 2; r++)
#pragma unroll
        for (int j = 0; j < NS; j++) sc[r][j] = 0.f;

    for (int c0 = 0; c0 < C; c0 += 16) {
        __syncthreads();
        for (int idx = tid; idx < 16 * T2; idx += 256) {
            int c = idx / T2, s = idx - c * T2;
            Kl[c][s] = K2[((size_t)b * C + c0 + c) * T2 + s];
        }
        if (tid < 128) {
            int rr = tid >> 4, c = tid & 15;
            Ql[rr][c] = Q3[((size_t)b * C + c0 + c) * T1 + (t0 + rr)];
        }
        __syncthreads();
#pragma unroll
        for (int c = 0; c < 16; c++) {
            float kv[NS];
#pragma unroll
            for (int j = 0; j < NS; j++) kv[j] = Kl[c][lane + 64 * j];
            float q0 = Ql[wave * 2 + 0][c];
            float q1 = Ql[wave * 2 + 1][c];
#pragma unroll
            for (int j = 0; j < NS; j++) {
                sc[0][j] = fmaf(q0, kv[j], sc[0][j]);
                sc[1][j] = fmaf(q1, kv[j], sc[1][j]);
            }
        }
    }

    float k2v[NS];
    int   mk[NS];
#pragma unroll
    for (int j = 0; j < NS; j++) {
        int s = lane + 64 * j;
        k2v[j] = (s < T2) ? k2s[b * T2 + s] : 0.f;
        mk[j]  = (s < T2) ? mask[b * T2 + s] : 1;
    }

    for (int r = 0; r < 2; r++) {
        int t = t0 + wave * 2 + r;
        float q2v = q2s[b * T1 + t];

        float scr[NS];
        float m = -INFINITY;
#pragma unroll
        for (int j = 0; j < NS; j++) {
            int s = lane + 64 * j;
            if (s < T2) {
                scr[j] = fmaf(1e-3f, sc[r][j], -5e-4f * (q2v + k2v[j]));
                m = fmaxf(m, scr[j]);
            } else {
                scr[j] = -INFINITY;
            }
        }
#pragma unroll
        for (int o = 32; o >= 1; o >>= 1) m = fmaxf(m, __shfl_xor(m, o));
        float sum = 0.f;
#pragma unroll
        for (int j = 0; j < NS; j++) {
            int s = lane + 64 * j;
            if (s < T2) sum += expf(scr[j] - m);
        }
#pragma unroll
        for (int o = 32; o >= 1; o >>= 1) sum += __shfl_xor(sum, o);
        float lse = m + logf(sum);

        const float* pr = prior + ((size_t)b * T1 + t) * T2;
        float* lpout = out_lp + ((size_t)b * T1 + t) * T2;
        float* atout = out_attn + ((size_t)b * T1 + t) * T2;

        float val[NS];
        float m2 = -INFINITY;
#pragma unroll
        for (int j = 0; j < NS; j++) {
            int s = lane + 64 * j;
            if (s < T2) {
                float lp = scr[j] - lse + logf(pr[s] + 1e-8f);
                lpout[s] = lp;
                val[j] = mk[j] ? -INFINITY : lp;
                m2 = fmaxf(m2, val[j]);
            } else {
                val[j] = -INFINITY;
            }
        }
#pragma unroll
        for (int o = 32; o >= 1; o >>= 1) m2 = fmaxf(m2, __shfl_xor(m2, o));
        float sum2 = 0.f;
#pragma unroll
        for (int j = 0; j < NS; j++) sum2 += expf(val[j] - m2);
#pragma unroll
        for (int o = 32; o >= 1; o >>= 1) sum2 += __shfl_xor(sum2, o);
        float inv = 1.f / sum2;
#pragma unroll
        for (int j = 0; j < NS; j++) {
            int s = lane + 64 * j;
            if (s < T2) atout[s] = expf(val[j] - m2) * inv;
        }
    }
}

// ---------------------------------------------------------------------------
extern "C" void kernel_launch(void* const* d_in, const int* in_sizes, int n_in,
                              void* d_out, int out_size, void* d_ws, size_t ws_size,
                              hipStream_t stream)
{
    (void)in_sizes; (void)n_in; (void)out_size; (void)ws_size;

    const float* queries = (const float*)d_in[0];
    const float* keys    = (const float*)d_in[1];
    const float* prior   = (const float*)d_in[2];
    const int*   mask    = (const int*)d_in[3];
    const float* kw1     = (const float*)d_in[4];
    const float* kb1     = (const float*)d_in[5];
    const float* kw2     = (const float*)d_in[6];
    const float* kb2     = (const float*)d_in[7];
    const float* qw1     = (const float*)d_in[8];
    const float* qb1     = (const float*)d_in[9];
    const float* qw2     = (const float*)d_in[10];
    const float* qb2     = (const float*)d_in[11];
    const float* qw3     = (const float*)d_in[12];
    const float* qb3     = (const float*)d_in[13];

    float* ws  = (float*)d_ws;
    float* K1  = ws;              // 13,107,200 f (later reused as Q1)
    float* K2  = ws + 13107200;   //  1,024,000 f
    float* Q2  = ws + 14131200;   //  4,096,000 f (Xt aliased here first)
    float* Q3  = ws + 18227200;   //  4,096,000 f (Wbf aliased here first)
    float* k2s = ws + 22323200;
    float* q2s = ws + 22336000;
    float* Q1  = K1;

    unsigned short* Xt  = (unsigned short*)Q2;  // 12932*512 bf16 = 3.31M f
    unsigned short* Wbf = (unsigned short*)Q3;  // 3*1024*512 bf16 = 0.79M f

    float* out_attn = (float*)d_out;
    float* out_lp   = out_attn + (size_t)32 * 1600 * 400;

    dim3 blk(256);

    // key path: convert -> MFMA conv1 -> f32 conv2
    convert_w<<<(1024 * 512 * 3 + 255) / 256, blk, 0, stream>>>(kw1, Wbf);
    convert_x<<<dim3(13, 16, 32), blk, 0, stream>>>(keys, Xt);
    zero_tail<<<8, blk, 0, stream>>>(Xt);
    conv1_mfma<<<dim3(101, 8), blk, 0, stream>>>(Wbf, Xt, kb1, K1);
    conv1d_tiled<1, false><<<dim3(7, 2, 32), blk, 0, stream>>>(K1, kw2, kb2, K2, 1024, 80, 400);
    // query path (overwrites Q1=K1 after conv2; Q2/Q3 after Xt/Wbf consumed)
    conv1d_tiled<3, true ><<<dim3(25, 3, 32), blk, 0, stream>>>(queries, qw1, qb1, Q1, 80, 160, 1600);
    conv1d_tiled<1, true ><<<dim3(25, 2, 32), blk, 0, stream>>>(Q1, qw2, qb2, Q2, 160, 80, 1600);
    conv1d_tiled<1, false><<<dim3(25, 2, 32), blk, 0, stream>>>(Q2, qw3, qb3, Q3, 80, 80, 1600);
    // squared norms
    sqsum_kernel<<<(32 * 400  + 255) / 256, blk, 0, stream>>>(K2, k2s, 80, 400, 32 * 400);
    sqsum_kernel<<<(32 * 1600 + 255) / 256, blk, 0, stream>>>(Q3, q2s, 80, 1600, 32 * 1600);
    // fused attention + softmaxes
    attn_kernel<<<dim3(200, 32), blk, 0, stream>>>(K2, Q3, k2s, q2s, prior, mask, out_attn, out_lp);
}

// Round 3
// 497.972 us; speedup vs baseline: 3.0880x; 1.5260x over previous
//
#include <hip/hip_runtime.h>
#include <math.h>

// ---------------------------------------------------------------------------
// ConvAttention (B=32, T1=1600, T2=400, n_mel=80, n_text=512, n_att=80)
// Round 3: ALL convs on bf16 MFMA (transposed-activation pipeline);
//          attn uses fast transcendentals (__expf/__logf) + cached exps.
// Layouts:
//   Xt / intermediate bf16: [b*Trow + t + PAD][Cpad]  (pad rows zero)
//   Wbf: [KTAP][CoutAlloc][Cpad]  (zero-padded)
//   final per-path f32: [b][c][t] for attn/sqsum kernels
// ---------------------------------------------------------------------------

typedef __attribute__((ext_vector_type(8))) short bf16x8;
typedef __attribute__((ext_vector_type(4))) float f32x4;

static __device__ __forceinline__ unsigned short f2bf(float f) {
    union { float f; unsigned u; } v; v.f = f;
    unsigned r = v.u + 0x7FFF + ((v.u >> 16) & 1);
    return (unsigned short)(r >> 16);
}

// ---------------- weight converter ----------------
// w f32 [Cout][Cin][KTAP] -> Wbf bf16 [KTAP][CoutAlloc][CinPad], zero-padded
__global__ __launch_bounds__(256) void convert_wgt(
    const float* __restrict__ w, unsigned short* __restrict__ Wbf,
    int Cout, int Cin, int KTAP, int CoutAlloc, int CinPad)
{
    int idx = blockIdx.x * 256 + threadIdx.x;
    int total = KTAP * CoutAlloc * CinPad;
    if (idx >= total) return;
    int d   = idx / (CoutAlloc * CinPad);
    int rem = idx - d * (CoutAlloc * CinPad);
    int co  = rem / CinPad;
    int ci  = rem - co * CinPad;
    float v = 0.f;
    if (co < Cout && ci < Cin)
        v = w[((size_t)co * Cin + ci) * KTAP + d];
    Wbf[idx] = f2bf(v);
}

// ---------------- input converter (transpose + pad) ----------------
// in f32 [B][C][T] -> Xt bf16 [b*Trow + tr][CinPad]; row tr holds t = tr-PAD
__global__ __launch_bounds__(256) void convert_inp(
    const float* __restrict__ in, unsigned short* __restrict__ Xt,
    int C, int CinPad, int T, int Trow, int PAD)
{
    __shared__ float s[32][33];
    int b = blockIdx.z, ci0 = blockIdx.y * 32, tr0 = blockIdx.x * 32;
    int tx = threadIdx.x & 31, ty = threadIdx.x >> 5; // 32 x 8
#pragma unroll
    for (int i = 0; i < 4; i++) {
        int c = ci0 + ty + 8 * i;
        int t_in = tr0 + tx - PAD;
        float v = (c < C && t_in >= 0 && t_in < T)
                    ? in[((size_t)b * C + c) * T + t_in] : 0.f;
        s[ty + 8 * i][tx] = v;
    }
    __syncthreads();
#pragma unroll
    for (int i = 0; i < 4; i++) {
        int tr = tr0 + ty + 8 * i;
        if (tr < Trow)
            Xt[((size_t)b * Trow + tr) * CinPad + ci0 + tx] = f2bf(s[tx][ty + 8 * i]);
    }
}

// zero the +4 tail rows of both transposed inputs
__global__ __launch_bounds__(256) void zero_tails(
    unsigned short* __restrict__ Xk, unsigned short* __restrict__ Xq)
{
    int i = blockIdx.x * 256 + threadIdx.x;
    if (i < 4 * 512) Xk[(size_t)12928 * 512 + i] = 0;
    if (i < 4 * 96)  Xq[(size_t)51328 * 96  + i] = 0;
}

// ---------------- generic conv-as-GEMM, bf16 MFMA ----------------
// A = Wbf [KTAP][CoutAlloc][CinPad], B = Xt rows (n + d), K = KTAP*CinPad.
// OUTMODE 0: bf16 out[(b*Tout+t)*OutStride + co], zero-fill co in [Cout,OutStride)
// OUTMODE 1: f32  out[((b*Cout)+co)*Tout + t]
template <int KTAP, int OUTMODE, bool RELU>
__global__ __launch_bounds__(256) void conv_mfma(
    const unsigned short* __restrict__ Wbf,
    const unsigned short* __restrict__ Xt,
    const float* __restrict__ bias,
    void* __restrict__ outv,
    int CinPad, int CoutAlloc, int Cout, int Trow, int Tout, int OutStride)
{
    constexpr int LDW = 40;   // staged LDS row stride (32+8 pad)
    constexpr int TRW = 140;  // transpose-epilogue row stride (16B-aligned)
    __shared__ unsigned short lds[OUTMODE == 0 ? 128 * TRW : 2 * 128 * LDW];
    unsigned short* Al = lds;
    unsigned short* Bl = lds + 128 * LDW;

    const int tid  = threadIdx.x;
    const int lane = tid & 63;
    const int wid  = tid >> 6;
    const int wm   = wid >> 1;
    const int wn   = wid & 1;
    const int co0  = blockIdx.y * 128;
    const int n0   = blockIdx.x * 128;

    const int r0 = tid >> 2;          // staging rows 0..63
    const int r1 = r0 + 64;           // 64..127
    const int q0 = (tid & 3) * 8;     // ci sub-offset

    const int nKc   = CinPad >> 5;
    const int nIter = KTAP * nKc;

    f32x4 acc[4][4] = {};

    bf16x8 ra0, ra1, rb0, rb1;
    ra0 = *(const bf16x8*)&Wbf[(size_t)(co0 + r0) * CinPad + q0];
    ra1 = *(const bf16x8*)&Wbf[(size_t)(co0 + r1) * CinPad + q0];
    rb0 = *(const bf16x8*)&Xt[(size_t)(n0 + r0) * CinPad + q0];
    rb1 = *(const bf16x8*)&Xt[(size_t)(n0 + r1) * CinPad + q0];

    const int fr = lane & 15;
    const int ko = (lane >> 4) * 8;

    int cc = 0, d = 0;
    for (int kk = 0; kk < nIter; kk++) {
        __syncthreads();
        *(bf16x8*)&Al[r0 * LDW + q0] = ra0;
        *(bf16x8*)&Al[r1 * LDW + q0] = ra1;
        *(bf16x8*)&Bl[r0 * LDW + q0] = rb0;
        *(bf16x8*)&Bl[r1 * LDW + q0] = rb1;
        __syncthreads();

        int ccn = cc + 1, dn = d;
        if (ccn == nKc) { ccn = 0; dn++; }
        if (kk < nIter - 1) {
            int ci0 = ccn * 32;
            ra0 = *(const bf16x8*)&Wbf[((size_t)dn * CoutAlloc + co0 + r0) * CinPad + ci0 + q0];
            ra1 = *(const bf16x8*)&Wbf[((size_t)dn * CoutAlloc + co0 + r1) * CinPad + ci0 + q0];
            rb0 = *(const bf16x8*)&Xt[(size_t)(n0 + dn + r0) * CinPad + ci0 + q0];
            rb1 = *(const bf16x8*)&Xt[(size_t)(n0 + dn + r1) * CinPad + ci0 + q0];
        }

        bf16x8 af[4], bfr[4];
#pragma unroll
        for (int mi = 0; mi < 4; mi++)
            af[mi] = *(const bf16x8*)&Al[(wm * 64 + mi * 16 + fr) * LDW + ko];
#pragma unroll
        for (int ni = 0; ni < 4; ni++)
            bfr[ni] = *(const bf16x8*)&Bl[(wn * 64 + ni * 16 + fr) * LDW + ko];
#pragma unroll
        for (int mi = 0; mi < 4; mi++)
#pragma unroll
            for (int ni = 0; ni < 4; ni++)
                acc[mi][ni] = __builtin_amdgcn_mfma_f32_16x16x32_bf16(
                    af[mi], bfr[ni], acc[mi][ni], 0, 0, 0);

        cc = ccn; d = dn;
    }

    if (OUTMODE == 1) {
        float* out = (float*)outv;
#pragma unroll
        for (int mi = 0; mi < 4; mi++) {
#pragma unroll
            for (int r = 0; r < 4; r++) {
                int co = co0 + wm * 64 + mi * 16 + (lane >> 4) * 4 + r;
                if (co >= Cout) continue;
                float bv = bias[co];
#pragma unroll
                for (int ni = 0; ni < 4; ni++) {
                    int n = n0 + wn * 64 + ni * 16 + fr;
                    int b = n / Trow;
                    int t = n - b * Trow;
                    if (t < Tout) {
                        float v = acc[mi][ni][r] + bv;
                        if (RELU) v = fmaxf(v, 0.f);
                        out[((size_t)b * Cout + co) * Tout + t] = v;
                    }
                }
            }
        }
    } else {
        // LDS-transpose epilogue -> contiguous bf16 row writes
        unsigned short* out = (unsigned short*)outv;
        __syncthreads(); // Al/Bl reads done; reuse lds as transpose tile
#pragma unroll
        for (int mi = 0; mi < 4; mi++) {
            int col = wm * 64 + mi * 16 + (lane >> 4) * 4;
#pragma unroll
            for (int ni = 0; ni < 4; ni++) {
                int row = wn * 64 + ni * 16 + fr;
                unsigned short pk[4];
#pragma unroll
                for (int r = 0; r < 4; r++) {
                    int co = co0 + col + r;
                    float v = 0.f;
                    if (co < Cout) {
                        v = acc[mi][ni][r] + bias[co];
                        if (RELU) v = fmaxf(v, 0.f);
                    }
                    pk[r] = f2bf(v);
                }
                *(unsigned long long*)&lds[row * TRW + col] = *(unsigned long long*)pk;
            }
        }
        __syncthreads();
        int rr = tid >> 1, h = tid & 1;
        int n = n0 + rr;
        int b = n / Trow;
        int t = n - b * Trow;
        int cw = OutStride - co0; if (cw > 128) cw = 128;
        if (t < Tout) {
            unsigned short* dst = out + ((size_t)b * Tout + t) * OutStride + co0;
#pragma unroll 8
            for (int c8 = h * 64; c8 < h * 64 + 64 && c8 < cw; c8 += 8)
                *(bf16x8*)&dst[c8] = *(const bf16x8*)&lds[rr * TRW + c8];
        }
    }
}

// ---------------- per-position squared channel sum ----------------
__global__ __launch_bounds__(256) void sqsum_kernel(
    const float* __restrict__ x, float* __restrict__ out, int C, int T, int total)
{
    int idx = blockIdx.x * 256 + threadIdx.x;
    if (idx >= total) return;
    int b = idx / T;
    int t = idx - b * T;
    const float* xb = x + (size_t)b * C * T + t;
    float s = 0.f;
    for (int c = 0; c < C; c++) {
        float v = xb[(size_t)c * T];
        s = fmaf(v, v, s);
    }
    out[idx] = s;
}

// ---------------- fused QK + softmax/logprob ----------------
#define NS 7
__global__ __launch_bounds__(256) void attn_kernel(
    const float* __restrict__ K2, const float* __restrict__ Q3,
    const float* __restrict__ k2s, const float* __restrict__ q2s,
    const float* __restrict__ prior, const int* __restrict__ mask,
    float* __restrict__ out_attn, float* __restrict__ out_lp)
{
    const int T1 = 1600, T2 = 400, C = 80;
    __shared__ float Kl[16][408];
    __shared__ float Ql[8][16];

    const int tid  = threadIdx.x;
    const int lane = tid & 63;
    const int wave = tid >> 6;
    const int b    = blockIdx.y;
    const int t0   = blockIdx.x * 8;

    float sc[2][NS];
#pragma unroll
    for (int r = 0; r < 2; r++)
#pragma unroll
        for (int j = 0; j < NS; j++) sc[r][j] = 0.f;

    for (int c0 = 0; c0 < C; c0 += 16) {
        __syncthreads();
        for (int idx = tid; idx < 16 * T2; idx += 256) {
            int c = idx / T2, s = idx - c * T2;
            Kl[c][s] = K2[((size_t)b * C + c0 + c) * T2 + s];
        }
        if (tid < 128) {
            int rr = tid >> 4, c = tid & 15;
            Ql[rr][c] = Q3[((size_t)b * C + c0 + c) * T1 + (t0 + rr)];
        }
        __syncthreads();
#pragma unroll
        for (int c = 0; c < 16; c++) {
            float kv[NS];
#pragma unroll
            for (int j = 0; j < NS; j++) kv[j] = Kl[c][lane + 64 * j];
            float q0 = Ql[wave * 2 + 0][c];
            float q1 = Ql[wave * 2 + 1][c];
#pragma unroll
            for (int j = 0; j < NS; j++) {
                sc[0][j] = fmaf(q0, kv[j], sc[0][j]);
                sc[1][j] = fmaf(q1, kv[j], sc[1][j]);
            }
        }
    }

    float k2v[NS];
    int   mk[NS];
#pragma unroll
    for (int j = 0; j < NS; j++) {
        int s = lane + 64 * j;
        k2v[j] = (s < T2) ? k2s[b * T2 + s] : 0.f;
        mk[j]  = (s < T2) ? mask[b * T2 + s] : 1;
    }

    for (int r = 0; r < 2; r++) {
        int t = t0 + wave * 2 + r;
        float q2v = q2s[b * T1 + t];

        float scr[NS];
        float m = -INFINITY;
#pragma unroll
        for (int j = 0; j < NS; j++) {
            int s = lane + 64 * j;
            if (s < T2) {
                scr[j] = fmaf(1e-3f, sc[r][j], -5e-4f * (q2v + k2v[j]));
                m = fmaxf(m, scr[j]);
            } else {
                scr[j] = -INFINITY;
            }
        }
#pragma unroll
        for (int o = 32; o >= 1; o >>= 1) m = fmaxf(m, __shfl_xor(m, o));
        float sum = 0.f;
#pragma unroll
        for (int j = 0; j < NS; j++) {
            int s = lane + 64 * j;
            if (s < T2) sum += __expf(scr[j] - m);
        }
#pragma unroll
        for (int o = 32; o >= 1; o >>= 1) sum += __shfl_xor(sum, o);
        float lse = m + __logf(sum);

        const float* pr = prior + ((size_t)b * T1 + t) * T2;
        float* lpout = out_lp + ((size_t)b * T1 + t) * T2;
        float* atout = out_attn + ((size_t)b * T1 + t) * T2;

        float val[NS];
        float m2 = -INFINITY;
#pragma unroll
        for (int j = 0; j < NS; j++) {
            int s = lane + 64 * j;
            if (s < T2) {
                float lp = scr[j] - lse + __logf(pr[s] + 1e-8f);
                lpout[s] = lp;
                val[j] = mk[j] ? -INFINITY : lp;
                m2 = fmaxf(m2, val[j]);
            } else {
                val[j] = -INFINITY;
            }
        }
#pragma unroll
        for (int o = 32; o >= 1; o >>= 1) m2 = fmaxf(m2, __shfl_xor(m2, o));
        float ex[NS];
        float sum2 = 0.f;
#pragma unroll
        for (int j = 0; j < NS; j++) { ex[j] = __expf(val[j] - m2); sum2 += ex[j]; }
#pragma unroll
        for (int o = 32; o >= 1; o >>= 1) sum2 += __shfl_xor(sum2, o);
        float inv = 1.f / sum2;
#pragma unroll
        for (int j = 0; j < NS; j++) {
            int s = lane + 64 * j;
            if (s < T2) atout[s] = ex[j] * inv;
        }
    }
}

// ---------------------------------------------------------------------------
extern "C" void kernel_launch(void* const* d_in, const int* in_sizes, int n_in,
                              void* d_out, int out_size, void* d_ws, size_t ws_size,
                              hipStream_t stream)
{
    (void)in_sizes; (void)n_in; (void)out_size; (void)ws_size;

    const float* queries = (const float*)d_in[0];
    const float* keys    = (const float*)d_in[1];
    const float* prior   = (const float*)d_in[2];
    const int*   mask    = (const int*)d_in[3];
    const float* kw1     = (const float*)d_in[4];
    const float* kb1     = (const float*)d_in[5];
    const float* kw2     = (const float*)d_in[6];
    const float* kb2     = (const float*)d_in[7];
    const float* qw1     = (const float*)d_in[8];
    const float* qb1     = (const float*)d_in[9];
    const float* qw2     = (const float*)d_in[10];
    const float* qb2     = (const float*)d_in[11];
    const float* qw3     = (const float*)d_in[12];
    const float* qb3     = (const float*)d_in[13];

    float* ws = (float*)d_ws;
    // region [0, 6.5536M): K1t bf16 [12800][1024]; later Q1t [51200][160] + Q2t [51200][96]
    unsigned short* K1t = (unsigned short*)(ws);
    unsigned short* Q1t = (unsigned short*)(ws);                     // 8.192M bf16
    unsigned short* Q2t = (unsigned short*)(ws + 4096000);           // 4.9152M bf16
    unsigned short* Xk  = (unsigned short*)(ws + 6553600);           // 12932*512 bf16
    unsigned short* Xq  = (unsigned short*)(ws + 6553600);           // 51332*96 bf16 (reuses Xk)
    unsigned short* Wk1 = (unsigned short*)(ws + 9869600);           // 3*1024*512
    unsigned short* Wk2 = (unsigned short*)(ws + 10656800);          // 128*1024
    float* K2  = ws + 10722336;                                      // 32*80*400
    float* k2s = ws + 11746336;                                      // 12800
    float* q2s = ws + 11759136;                                      // 51200
    float* Q3  = ws + 11810336;                                      // 32*80*1600
    unsigned short* Wq1 = (unsigned short*)(ws + 15906336);          // 3*256*96
    unsigned short* Wq2 = (unsigned short*)(ws + 15943200);          // 128*160
    unsigned short* Wq3 = (unsigned short*)(ws + 15953440);          // 128*96
    // total ~15.96M floats = 63.8 MB

    float* out_attn = (float*)d_out;
    float* out_lp   = out_attn + (size_t)32 * 1600 * 400;

    dim3 blk(256);

    // weight conversions
    convert_wgt<<<(3 * 1024 * 512 + 255) / 256, blk, 0, stream>>>(kw1, Wk1, 1024, 512, 3, 1024, 512);
    convert_wgt<<<(1 * 128 * 1024 + 255) / 256, blk, 0, stream>>>(kw2, Wk2, 80, 1024, 1, 128, 1024);
    convert_wgt<<<(3 * 256 * 96   + 255) / 256, blk, 0, stream>>>(qw1, Wq1, 160, 80, 3, 256, 96);
    convert_wgt<<<(1 * 128 * 160  + 255) / 256, blk, 0, stream>>>(qw2, Wq2, 80, 160, 1, 128, 160);
    convert_wgt<<<(1 * 128 * 96   + 255) / 256, blk, 0, stream>>>(qw3, Wq3, 80, 80, 1, 128, 96);

    // key path
    convert_inp<<<dim3(13, 16, 32), blk, 0, stream>>>(keys, Xk, 512, 512, 400, 404, 1);
    zero_tails<<<8, blk, 0, stream>>>(Xk, Xq); // Xq tail zeroed again after convert_inp(q)
    conv_mfma<3, 0, true ><<<dim3(101, 8), blk, 0, stream>>>(Wk1, Xk, kb1, K1t, 512, 1024, 1024, 404, 400, 1024);
    conv_mfma<1, 1, false><<<dim3(100, 1), blk, 0, stream>>>(Wk2, K1t, kb2, K2, 1024, 128, 80, 400, 400, 0);

    // query path (Xq over Xk region; Q1t/Q2t over K1t region)
    convert_inp<<<dim3(51, 3, 32), blk, 0, stream>>>(queries, Xq, 80, 96, 1600, 1604, 1);
    zero_tails<<<8, blk, 0, stream>>>(Xk, Xq);
    conv_mfma<3, 0, true ><<<dim3(401, 2), blk, 0, stream>>>(Wq1, Xq, qb1, Q1t, 96, 256, 160, 1604, 1600, 160);
    conv_mfma<1, 0, true ><<<dim3(400, 1), blk, 0, stream>>>(Wq2, Q1t, qb2, Q2t, 160, 128, 80, 1600, 1600, 96);
    conv_mfma<1, 1, false><<<dim3(400, 1), blk, 0, stream>>>(Wq3, Q2t, qb3, Q3, 96, 128, 80, 1600, 1600, 0);

    // squared norms
    sqsum_kernel<<<(32 * 400  + 255) / 256, blk, 0, stream>>>(K2, k2s, 80, 400, 32 * 400);
    sqsum_kernel<<<(32 * 1600 + 255) / 256, blk, 0, stream>>>(Q3, q2s, 80, 1600, 32 * 1600);

    // fused attention + softmaxes
    attn_kernel<<<dim3(200, 32), blk, 0, stream>>>(K2, Q3, k2s, q2s, prior, mask, out_attn, out_lp);
}

// Round 4
// 292.486 us; speedup vs baseline: 5.2575x; 1.7026x over previous
//
#include <hip/hip_runtime.h>
#include <math.h>

// ---------------------------------------------------------------------------
// ConvAttention (B=32, T1=1600, T2=400, n_mel=80, n_text=512, n_att=80)
// Round 4: attention rewritten on MFMA (scores via 16x16x32 bf16 into LDS,
//          fused softmax). q2 term dropped (exact shift-invariance).
//          K/Q heads kept in transposed bf16 [b*T+t][96] end-to-end.
// ---------------------------------------------------------------------------

typedef __attribute__((ext_vector_type(8))) short bf16x8;
typedef __attribute__((ext_vector_type(4))) float f32x4;

static __device__ __forceinline__ unsigned short f2bf(float f) {
    union { float f; unsigned u; } v; v.f = f;
    unsigned r = v.u + 0x7FFF + ((v.u >> 16) & 1);
    return (unsigned short)(r >> 16);
}
static __device__ __forceinline__ float bf2f(unsigned short h) {
    union { unsigned u; float f; } v; v.u = ((unsigned)h) << 16;
    return v.f;
}

// ---------------- weight converter ----------------
__global__ __launch_bounds__(256) void convert_wgt(
    const float* __restrict__ w, unsigned short* __restrict__ Wbf,
    int Cout, int Cin, int KTAP, int CoutAlloc, int CinPad)
{
    int idx = blockIdx.x * 256 + threadIdx.x;
    int total = KTAP * CoutAlloc * CinPad;
    if (idx >= total) return;
    int d   = idx / (CoutAlloc * CinPad);
    int rem = idx - d * (CoutAlloc * CinPad);
    int co  = rem / CinPad;
    int ci  = rem - co * CinPad;
    float v = 0.f;
    if (co < Cout && ci < Cin)
        v = w[((size_t)co * Cin + ci) * KTAP + d];
    Wbf[idx] = f2bf(v);
}

// ---------------- input converter (transpose + pad) ----------------
__global__ __launch_bounds__(256) void convert_inp(
    const float* __restrict__ in, unsigned short* __restrict__ Xt,
    int C, int CinPad, int T, int Trow, int PAD)
{
    __shared__ float s[32][33];
    int b = blockIdx.z, ci0 = blockIdx.y * 32, tr0 = blockIdx.x * 32;
    int tx = threadIdx.x & 31, ty = threadIdx.x >> 5;
#pragma unroll
    for (int i = 0; i < 4; i++) {
        int c = ci0 + ty + 8 * i;
        int t_in = tr0 + tx - PAD;
        float v = (c < C && t_in >= 0 && t_in < T)
                    ? in[((size_t)b * C + c) * T + t_in] : 0.f;
        s[ty + 8 * i][tx] = v;
    }
    __syncthreads();
#pragma unroll
    for (int i = 0; i < 4; i++) {
        int tr = tr0 + ty + 8 * i;
        if (tr < Trow)
            Xt[((size_t)b * Trow + tr) * CinPad + ci0 + tx] = f2bf(s[tx][ty + 8 * i]);
    }
}

__global__ __launch_bounds__(256) void zero_tail_k(unsigned short* __restrict__ Xk)
{
    int i = blockIdx.x * 256 + threadIdx.x;
    if (i < 4 * 512) Xk[(size_t)12928 * 512 + i] = 0;
}
__global__ __launch_bounds__(256) void zero_tail_q(unsigned short* __restrict__ Xq)
{
    int i = blockIdx.x * 256 + threadIdx.x;
    if (i < 4 * 96) Xq[(size_t)51328 * 96 + i] = 0;
}

// ---------------- generic conv-as-GEMM, bf16 MFMA ----------------
// OUTMODE 0: bf16 out[(b*Tout+t)*OutStride + co], zero-fill co in [Cout,OutStride)
template <int KTAP, bool RELU>
__global__ __launch_bounds__(256) void conv_mfma(
    const unsigned short* __restrict__ Wbf,
    const unsigned short* __restrict__ Xt,
    const float* __restrict__ bias,
    unsigned short* __restrict__ out,
    int CinPad, int CoutAlloc, int Cout, int Trow, int Tout, int OutStride)
{
    constexpr int LDW = 40;
    constexpr int TRW = 140;
    __shared__ unsigned short lds[128 * TRW];
    unsigned short* Al = lds;
    unsigned short* Bl = lds + 128 * LDW;

    const int tid  = threadIdx.x;
    const int lane = tid & 63;
    const int wid  = tid >> 6;
    const int wm   = wid >> 1;
    const int wn   = wid & 1;
    const int co0  = blockIdx.y * 128;
    const int n0   = blockIdx.x * 128;

    const int r0 = tid >> 2;
    const int r1 = r0 + 64;
    const int q0 = (tid & 3) * 8;

    const int nKc   = CinPad >> 5;
    const int nIter = KTAP * nKc;

    f32x4 acc[4][4] = {};

    bf16x8 ra0, ra1, rb0, rb1;
    ra0 = *(const bf16x8*)&Wbf[(size_t)(co0 + r0) * CinPad + q0];
    ra1 = *(const bf16x8*)&Wbf[(size_t)(co0 + r1) * CinPad + q0];
    rb0 = *(const bf16x8*)&Xt[(size_t)(n0 + r0) * CinPad + q0];
    rb1 = *(const bf16x8*)&Xt[(size_t)(n0 + r1) * CinPad + q0];

    const int fr = lane & 15;
    const int ko = (lane >> 4) * 8;

    int cc = 0, d = 0;
    for (int kk = 0; kk < nIter; kk++) {
        __syncthreads();
        *(bf16x8*)&Al[r0 * LDW + q0] = ra0;
        *(bf16x8*)&Al[r1 * LDW + q0] = ra1;
        *(bf16x8*)&Bl[r0 * LDW + q0] = rb0;
        *(bf16x8*)&Bl[r1 * LDW + q0] = rb1;
        __syncthreads();

        int ccn = cc + 1, dn = d;
        if (ccn == nKc) { ccn = 0; dn++; }
        if (kk < nIter - 1) {
            int ci0 = ccn * 32;
            ra0 = *(const bf16x8*)&Wbf[((size_t)dn * CoutAlloc + co0 + r0) * CinPad + ci0 + q0];
            ra1 = *(const bf16x8*)&Wbf[((size_t)dn * CoutAlloc + co0 + r1) * CinPad + ci0 + q0];
            rb0 = *(const bf16x8*)&Xt[(size_t)(n0 + dn + r0) * CinPad + ci0 + q0];
            rb1 = *(const bf16x8*)&Xt[(size_t)(n0 + dn + r1) * CinPad + ci0 + q0];
        }

        bf16x8 af[4], bfr[4];
#pragma unroll
        for (int mi = 0; mi < 4; mi++)
            af[mi] = *(const bf16x8*)&Al[(wm * 64 + mi * 16 + fr) * LDW + ko];
#pragma unroll
        for (int ni = 0; ni < 4; ni++)
            bfr[ni] = *(const bf16x8*)&Bl[(wn * 64 + ni * 16 + fr) * LDW + ko];
#pragma unroll
        for (int mi = 0; mi < 4; mi++)
#pragma unroll
            for (int ni = 0; ni < 4; ni++)
                acc[mi][ni] = __builtin_amdgcn_mfma_f32_16x16x32_bf16(
                    af[mi], bfr[ni], acc[mi][ni], 0, 0, 0);

        cc = ccn; d = dn;
    }

    // LDS-transpose epilogue -> contiguous bf16 row writes
    __syncthreads();
#pragma unroll
    for (int mi = 0; mi < 4; mi++) {
        int col = wm * 64 + mi * 16 + (lane >> 4) * 4;
#pragma unroll
        for (int ni = 0; ni < 4; ni++) {
            int row = wn * 64 + ni * 16 + fr;
            unsigned short pk[4];
#pragma unroll
            for (int r = 0; r < 4; r++) {
                int co = co0 + col + r;
                float v = 0.f;
                if (co < Cout) {
                    v = acc[mi][ni][r] + bias[co];
                    if (RELU) v = fmaxf(v, 0.f);
                }
                pk[r] = f2bf(v);
            }
            *(unsigned long long*)&lds[row * TRW + col] = *(unsigned long long*)pk;
        }
    }
    __syncthreads();
    int rr = tid >> 1, h = tid & 1;
    int n = n0 + rr;
    int b = n / Trow;
    int t = n - b * Trow;
    int cw = OutStride - co0; if (cw > 128) cw = 128;
    if (t < Tout) {
        unsigned short* dst = out + ((size_t)b * Tout + t) * OutStride + co0;
#pragma unroll 8
        for (int c8 = h * 64; c8 < h * 64 + 64 && c8 < cw; c8 += 8)
            *(bf16x8*)&dst[c8] = *(const bf16x8*)&lds[rr * TRW + c8];
    }
}

// ---------------- k2 from bf16 Kt ----------------
__global__ __launch_bounds__(256) void k2_kernel(
    const unsigned short* __restrict__ Kt, float* __restrict__ k2s)
{
    int lane = threadIdx.x & 63, w = threadIdx.x >> 6;
    int row = blockIdx.x * 64 + w * 16 + (lane >> 2);
    int c0 = (lane & 3) * 24;
    const unsigned short* p = Kt + (size_t)row * 96 + c0;
    float s = 0.f;
#pragma unroll
    for (int i = 0; i < 3; i++) {
        bf16x8 v = *(const bf16x8*)&p[i * 8];
#pragma unroll
        for (int e = 0; e < 8; e++) {
            float f = bf2f((unsigned short)v[e]);
            s = fmaf(f, f, s);
        }
    }
    s += __shfl_xor(s, 1);
    s += __shfl_xor(s, 2);
    if ((lane & 3) == 0) k2s[row] = s;
}

// ---------------- fused MFMA-QK + softmax/logprob ----------------
// Block: 512 thr (8 waves) x one 32-row t-tile of one b.
// scores = 1e-3*qk - 5e-4*k2[s]   (q2 cancels in both softmaxes)
#define NS 7
#define SCW 404
__global__ __launch_bounds__(512) void attn_v2(
    const unsigned short* __restrict__ Kt,   // [32*400][96] bf16
    const unsigned short* __restrict__ Qt,   // [32*1600][96] bf16
    const float* __restrict__ k2s,           // [32*400]
    const float* __restrict__ prior, const int* __restrict__ mask,
    float* __restrict__ out_attn, float* __restrict__ out_lp)
{
    const int T1 = 1600, T2 = 400;
    __shared__ float Sc[32 * SCW];

    const int tid  = threadIdx.x;
    const int lane = tid & 63;
    const int wid  = tid >> 6;
    const int b    = blockIdx.y;
    const int t0   = blockIdx.x * 32;
    const int fr   = lane & 15;
    const int ko   = (lane >> 4) * 8;

    // Q fragments: 2 t-subtiles x 3 k-steps (k pads 80..95 are zero)
    bf16x8 qf[2][3];
#pragma unroll
    for (int ts = 0; ts < 2; ts++)
#pragma unroll
        for (int kk = 0; kk < 3; kk++)
            qf[ts][kk] = *(const bf16x8*)&Qt[((size_t)b * T1 + t0 + ts * 16 + fr) * 96 + kk * 32 + ko];

    // QK^T into LDS scores (25 s-tiles of 16 over 8 waves)
    for (int st = wid; st < 25; st += 8) {
        f32x4 acc0 = {}, acc1 = {};
#pragma unroll
        for (int kk = 0; kk < 3; kk++) {
            bf16x8 kf = *(const bf16x8*)&Kt[((size_t)b * T2 + st * 16 + fr) * 96 + kk * 32 + ko];
            acc0 = __builtin_amdgcn_mfma_f32_16x16x32_bf16(kf, qf[0][kk], acc0, 0, 0, 0);
            acc1 = __builtin_amdgcn_mfma_f32_16x16x32_bf16(kf, qf[1][kk], acc1, 0, 0, 0);
        }
        int sbase = st * 16 + (lane >> 4) * 4;
        float4 kv = *(const float4*)&k2s[b * T2 + sbase];
        float4 w0, w1;
        w0.x = fmaf(1e-3f, acc0[0], -5e-4f * kv.x);
        w0.y = fmaf(1e-3f, acc0[1], -5e-4f * kv.y);
        w0.z = fmaf(1e-3f, acc0[2], -5e-4f * kv.z);
        w0.w = fmaf(1e-3f, acc0[3], -5e-4f * kv.w);
        w1.x = fmaf(1e-3f, acc1[0], -5e-4f * kv.x);
        w1.y = fmaf(1e-3f, acc1[1], -5e-4f * kv.y);
        w1.z = fmaf(1e-3f, acc1[2], -5e-4f * kv.z);
        w1.w = fmaf(1e-3f, acc1[3], -5e-4f * kv.w);
        *(float4*)&Sc[fr * SCW + sbase]        = w0;
        *(float4*)&Sc[(16 + fr) * SCW + sbase] = w1;
    }

    // mask/key terms (per lane, shared by all rows)
    int mk[NS];
#pragma unroll
    for (int j = 0; j < NS; j++) {
        int s = lane + 64 * j;
        mk[j] = (s < T2) ? mask[b * T2 + s] : 1;
    }

    __syncthreads();

    // softmax: 4 t-rows per wave
    for (int r = 0; r < 4; r++) {
        int tloc = wid * 4 + r;
        int t = t0 + tloc;

        float scr[NS];
        float m = -INFINITY;
#pragma unroll
        for (int j = 0; j < NS; j++) {
            int s = lane + 64 * j;
            if (s < T2) {
                scr[j] = Sc[tloc * SCW + s];
                m = fmaxf(m, scr[j]);
            } else {
                scr[j] = -INFINITY;
            }
        }
#pragma unroll
        for (int o = 32; o >= 1; o >>= 1) m = fmaxf(m, __shfl_xor(m, o));
        float sum = 0.f;
#pragma unroll
        for (int j = 0; j < NS; j++) {
            int s = lane + 64 * j;
            if (s < T2) sum += __expf(scr[j] - m);
        }
#pragma unroll
        for (int o = 32; o >= 1; o >>= 1) sum += __shfl_xor(sum, o);
        float lse = m + __logf(sum);

        const float* pr = prior + ((size_t)b * T1 + t) * T2;
        float* lpout = out_lp + ((size_t)b * T1 + t) * T2;
        float* atout = out_attn + ((size_t)b * T1 + t) * T2;

        float val[NS];
        float m2 = -INFINITY;
#pragma unroll
        for (int j = 0; j < NS; j++) {
            int s = lane + 64 * j;
            if (s < T2) {
                float lp = scr[j] - lse + __logf(pr[s] + 1e-8f);
                lpout[s] = lp;
                val[j] = mk[j] ? -INFINITY : lp;
                m2 = fmaxf(m2, val[j]);
            } else {
                val[j] = -INFINITY;
            }
        }
#pragma unroll
        for (int o = 32; o >= 1; o >>= 1) m2 = fmaxf(m2, __shfl_xor(m2, o));
        float ex[NS];
        float sum2 = 0.f;
#pragma unroll
        for (int j = 0; j < NS; j++) { ex[j] = __expf(val[j] - m2); sum2 += ex[j]; }
#pragma unroll
        for (int o = 32; o >= 1; o >>= 1) sum2 += __shfl_xor(sum2, o);
        float inv = 1.f / sum2;
#pragma unroll
        for (int j = 0; j < NS; j++) {
            int s = lane + 64 * j;
            if (s < T2) atout[s] = ex[j] * inv;
        }
    }
}

// ---------------------------------------------------------------------------
extern "C" void kernel_launch(void* const* d_in, const int* in_sizes, int n_in,
                              void* d_out, int out_size, void* d_ws, size_t ws_size,
                              hipStream_t stream)
{
    (void)in_sizes; (void)n_in; (void)out_size; (void)ws_size;

    const float* queries = (const float*)d_in[0];
    const float* keys    = (const float*)d_in[1];
    const float* prior   = (const float*)d_in[2];
    const int*   mask    = (const int*)d_in[3];
    const float* kw1     = (const float*)d_in[4];
    const float* kb1     = (const float*)d_in[5];
    const float* kw2     = (const float*)d_in[6];
    const float* kb2     = (const float*)d_in[7];
    const float* qw1     = (const float*)d_in[8];
    const float* qb1     = (const float*)d_in[9];
    const float* qw2     = (const float*)d_in[10];
    const float* qb2     = (const float*)d_in[11];
    const float* qw3     = (const float*)d_in[12];
    const float* qb3     = (const float*)d_in[13];

    float* ws = (float*)d_ws;
    // word offsets (f32 units)
    unsigned short* K1t = (unsigned short*)(ws);                 // [12800][1024] bf16 (R1)
    unsigned short* Q1t = (unsigned short*)(ws);                 // [51200][160] bf16 (R1 reuse)
    unsigned short* Xk  = (unsigned short*)(ws + 6553600);       // [12932][512] bf16 (R2)
    unsigned short* Xq  = (unsigned short*)(ws + 6553600);       // [51332][96] bf16 (R2 reuse)
    unsigned short* Qt  = (unsigned short*)(ws + 6553600);       // [51200][96] bf16 (R2 reuse)
    unsigned short* Kt  = (unsigned short*)(ws + 9864192);       // [12800][96] bf16
    unsigned short* Q2t = (unsigned short*)(ws + 10479360);      // [51200][96] bf16
    unsigned short* Wk1 = (unsigned short*)(ws + 12936960);      // 3*1024*512
    unsigned short* Wk2 = (unsigned short*)(ws + 13723392);      // 128*1024
    unsigned short* Wq1 = (unsigned short*)(ws + 13788928);      // 3*256*96
    unsigned short* Wq2 = (unsigned short*)(ws + 13825792);      // 128*160
    unsigned short* Wq3 = (unsigned short*)(ws + 13836032);      // 128*96
    float*          k2s = ws + 13842176;                         // 12800 f32
    // end: 13,854,976 words = 55.4 MB

    float* out_attn = (float*)d_out;
    float* out_lp   = out_attn + (size_t)32 * 1600 * 400;

    dim3 blk(256);

    // weight conversions
    convert_wgt<<<(3 * 1024 * 512 + 255) / 256, blk, 0, stream>>>(kw1, Wk1, 1024, 512, 3, 1024, 512);
    convert_wgt<<<(1 * 128 * 1024 + 255) / 256, blk, 0, stream>>>(kw2, Wk2, 80, 1024, 1, 128, 1024);
    convert_wgt<<<(3 * 256 * 96   + 255) / 256, blk, 0, stream>>>(qw1, Wq1, 160, 80, 3, 256, 96);
    convert_wgt<<<(1 * 128 * 160  + 255) / 256, blk, 0, stream>>>(qw2, Wq2, 80, 160, 1, 128, 160);
    convert_wgt<<<(1 * 128 * 96   + 255) / 256, blk, 0, stream>>>(qw3, Wq3, 80, 80, 1, 128, 96);

    // key path
    convert_inp<<<dim3(13, 16, 32), blk, 0, stream>>>(keys, Xk, 512, 512, 400, 404, 1);
    zero_tail_k<<<8, blk, 0, stream>>>(Xk);
    conv_mfma<3, true ><<<dim3(101, 8), blk, 0, stream>>>(Wk1, Xk, kb1, K1t, 512, 1024, 1024, 404, 400, 1024);
    conv_mfma<1, false><<<dim3(100, 1), blk, 0, stream>>>(Wk2, K1t, kb2, Kt, 1024, 128, 80, 400, 400, 96);
    k2_kernel<<<200, blk, 0, stream>>>(Kt, k2s);

    // query path (Xq over dead Xk; Q1t over dead K1t; Qt over dead Xq)
    convert_inp<<<dim3(51, 3, 32), blk, 0, stream>>>(queries, Xq, 80, 96, 1600, 1604, 1);
    zero_tail_q<<<8, blk, 0, stream>>>(Xq);
    conv_mfma<3, true ><<<dim3(401, 2), blk, 0, stream>>>(Wq1, Xq, qb1, Q1t, 96, 256, 160, 1604, 1600, 160);
    conv_mfma<1, true ><<<dim3(400, 1), blk, 0, stream>>>(Wq2, Q1t, qb2, Q2t, 160, 128, 80, 1600, 1600, 96);
    conv_mfma<1, false><<<dim3(400, 1), blk, 0, stream>>>(Wq3, Q2t, qb3, Qt, 96, 128, 80, 1600, 1600, 96);

    // fused attention + softmaxes
    attn_v2<<<dim3(50, 32), dim3(512), 0, stream>>>(Kt, Qt, k2s, prior, mask, out_attn, out_lp);
}